// Round 1
// 185.432 us; speedup vs baseline: 1.1021x; 1.1021x over previous
//
#include <hip/hip_runtime.h>

// TrigHashGrid: B=1048576, IN_DIM=3, M=3, N=16, C=2, W=1000, A=-0.75
// R5: occupancy doubling. R4 was latency-bound (VALUBusy 28%, LDS pipe ~25%,
// HBM 20% -- nothing saturated; Occupancy 36%). The 64KB LDS tile is
// per-block but wave capacity is per-CU: BLK 512->1024 keeps 2 blocks/CU
// (2x64KB = 128.5KB <= 160KB) but lifts waves/CU 16 -> 32 (100%).
// Same 8-level tile, same padded rows, same 8n x 8b wave mapping (full 64B
// output lines per b), same numerics. VGPR=52 <= 64 so 8 waves/SIMD legal.
// Grid 1024 = 512 b-groups x 2 halves; 16 iters/thread unchanged.

constexpr int B_TOT = 1048576;
constexpr float A_C = -0.75f;

#define BLK 1024
#define WPAD 1004            // 2 + 1000 + 2
#define RSTRIDE (WPAD * 2)   // 2008 floats per level row (w-major, c inner)

__device__ __forceinline__ float hw_sin(float a) {
    // sin(a) = v_sin_f32(fract(a / 2pi)); v_fract wraps negatives correctly.
    float rev = a * 0.15915494309189535f;
    rev = __builtin_amdgcn_fractf(rev);
    return __builtin_amdgcn_sinf(rev);
}

__global__ __launch_bounds__(BLK, 8)
void trig_hashgrid(const float* __restrict__ x, const float* __restrict__ grids,
                   const float* __restrict__ G, const float* __restrict__ H,
                   float* __restrict__ out)
{
    __shared__ float lds[8 * RSTRIDE];        // 64256 B -> 2 blocks/CU (threads also cap at 2)
    const int tid  = threadIdx.x;
    const int half = blockIdx.x & 1;          // which 8 of the 16 levels
    const int blk  = blockIdx.x >> 1;         // 0..511

    // Zero the 8 pad floats per level row (padded w {0,1,1002,1003} x c {0,1}).
    if (tid < 64) {
        int nl = tid >> 3, j = tid & 7;
        int off = (j < 4) ? j : (RSTRIDE - 8 + j);
        lds[nl * RSTRIDE + off] = 0.0f;
    }
    // Stage grids[half*8 .. half*8+8): strip per row; 128 lanes/row read
    // consecutive w (coalesced 512B); LDS writes stride 8B (2-way, free).
    {
        int row = tid >> 7;                   // 0..7 (level within half)
        int j   = tid & 127;
        const float* gsrc = grids + half * 16000 + row * 2000;
        float* ldst = lds + row * RSTRIDE;
#pragma unroll
        for (int c = 0; c < 2; ++c)
            for (int w = j; w < 1000; w += 128)
                ldst[(w + 2) * 2 + c] = gsrc[c * 1000 + w];
    }

    const int n_loc = tid & 7;
    const int n     = half * 8 + n_loc;       // fixed per thread
    const int g     = tid >> 3;               // 0..127

    // Per-level frequencies/phases in registers (reused 16 iters).
    float G0[3], G1[3], G2[3], Hr[3];
#pragma unroll
    for (int m = 0; m < 3; ++m) {
        G0[m] = G[0 * 48 + m * 16 + n];
        G1[m] = G[1 * 48 + m * 16 + n];
        G2[m] = G[2 * 48 + m * 16 + n];
        Hr[m] = H[m * 16 + n];
    }
    __syncthreads();

    float2* __restrict__ out2 = (float2*)out;
    const float* lrow = &lds[n_loc * RSTRIDE];

    // 16 iterations: b stride = 512 b-groups * 128 b's.
#pragma unroll 2
    for (int b = blk * 128 + g; b < B_TOT; b += 512 * 128) {
        float x0 = x[b * 3 + 0];
        float x1 = x[b * 3 + 1];
        float x2 = x[b * 3 + 2];

        float p = 1.0f;
#pragma unroll
        for (int m = 0; m < 3; ++m) {
            float a = fmaf(x0, G0[m], fmaf(x1, G1[m], fmaf(x2, G2[m], Hr[m])));
            p *= hw_sin(a);
        }

        float ix = fmaf(p, 500.0f, 499.5f);                // [-0.5, 999.5]
        float xf = floorf(ix);
        float t  = ix - xf;
        int base = (int)xf;                                // [-1, 999]
        base = min(max(base, -1), 999);                    // cheap insurance

        // Factored Keys weights:
        // w0 = A t u^2, w3 = A t^2 u, w1 = ((A+2)t-(A+3))t^2+1, w2 = 1-rest
        float u   = 1.0f - t;
        float tu  = t * u;
        float atu = A_C * tu;
        float w0  = atu * u;
        float w3  = atu * t;
        float w1  = fmaf(fmaf(A_C + 2.0f, t, -(A_C + 3.0f)), t * t, 1.0f);
        float w2  = 1.0f - w0 - w1 - w3;

        // 4 consecutive padded taps starting at padded index base+1 >= 0.
        const float* tap = lrow + (base + 1) * 2;
        float2 v0 = *(const float2*)(tap + 0);
        float2 v1 = *(const float2*)(tap + 2);
        float2 v2 = *(const float2*)(tap + 4);
        float2 v3 = *(const float2*)(tap + 6);

        float o0 = v0.x * w0, o1 = v0.y * w0;
        o0 = fmaf(v1.x, w1, o0); o1 = fmaf(v1.y, w1, o1);
        o0 = fmaf(v2.x, w2, o0); o1 = fmaf(v2.y, w2, o1);
        o0 = fmaf(v3.x, w3, o0); o1 = fmaf(v3.y, w3, o1);

        // out[b, n, c] flat = b*32 + n*2 + c -> float2 at b*16 + n
        // wave = 8 b x 8 n -> full 64B lines per b.
        out2[b * 16 + n] = make_float2(o0, o1);
    }
}

extern "C" void kernel_launch(void* const* d_in, const int* in_sizes, int n_in,
                              void* d_out, int out_size, void* d_ws, size_t ws_size,
                              hipStream_t stream) {
    const float* x     = (const float*)d_in[0];
    const float* grids = (const float*)d_in[1];
    const float* G     = (const float*)d_in[2];
    const float* H     = (const float*)d_in[3];
    float* out = (float*)d_out;
    trig_hashgrid<<<1024, BLK, 0, stream>>>(x, grids, G, H, out);
}

// Round 2
// 183.947 us; speedup vs baseline: 1.1110x; 1.0081x over previous
//
#include <hip/hip_runtime.h>
#include <hip/hip_fp16.h>

// TrigHashGrid: B=1048576, IN_DIM=3, M=3, N=16, C=2, W=1000, A=-0.75
// R6: latency-chain surgery. R5 (32 waves/CU) only bought 21% -- no pipe
// saturated (VALU 28%, LDS ~27%, HBM 20%) => dependent-chain latency bound:
// x load (~500-900cy) -> sin pipeline -> data-dependent ds_read -> store.
// Two fixes:
//  (1) 1-ahead software pipeline of the x[] load: next iter's 3 dwords are
//      issued before current iter's compute consumes x -- removes global
//      latency from the chain (+6 VGPR, stays <=64 for 8 waves/SIMD).
//  (2) fp16 __half2 LDS grid (c0,c1 packed in one dword): taps become 4x
//      ds_read_b32 (4B random) vs 4x ds_read_b64 (8B random) -- random-bank
//      serialization ~9.2 -> ~3.5 extra cyc/access; LDS 64KB -> 32KB.
//      Error: grids ~0.1*N(0,1), fp16 quant <=2.4e-4 * sum|w|~1.2 => +3e-4
//      absmax on 0.0039, threshold 8.87e-3.
// Same 8n x 8b wave mapping (1KB contiguous stores per wave), same grid.

constexpr int B_TOT = 1048576;
constexpr float A_C = -0.75f;

#define BLK 1024
#define WPAD 1004            // 2 + 1000 + 2 positions, one __half2 each

__device__ __forceinline__ float hw_sin(float a) {
    // sin(a) = v_sin_f32(fract(a / 2pi)); v_fract wraps negatives correctly.
    float rev = a * 0.15915494309189535f;
    rev = __builtin_amdgcn_fractf(rev);
    return __builtin_amdgcn_sinf(rev);
}

__global__ __launch_bounds__(BLK, 8)
void trig_hashgrid(const float* __restrict__ x, const float* __restrict__ grids,
                   const float* __restrict__ G, const float* __restrict__ H,
                   float* __restrict__ out)
{
    __shared__ __half2 lds[8 * WPAD];         // 32128 B
    const int tid  = threadIdx.x;
    const int half = blockIdx.x & 1;          // which 8 of the 16 levels
    const int blk  = blockIdx.x >> 1;         // 0..511

    // Zero the 4 pad positions per level row (padded w {0,1,1002,1003}).
    if (tid < 32) {
        int nl = tid >> 2, j = tid & 3;
        int off = (j < 2) ? j : (WPAD - 4 + j);
        lds[nl * WPAD + off] = __floats2half2_rn(0.0f, 0.0f);
    }
    // Stage grids[half*8 .. half*8+8) as packed half2(c0,c1) per w position.
    // 128 lanes/row read consecutive w (coalesced); tiny one-time cost.
    {
        int row = tid >> 7;                   // 0..7 (level within half)
        int j   = tid & 127;
        const float* gsrc = grids + half * 16000 + row * 2000;
        __half2* ldst = lds + row * WPAD;
        for (int w = j; w < 1000; w += 128)
            ldst[w + 2] = __floats2half2_rn(gsrc[w], gsrc[1000 + w]);
    }

    const int n_loc = tid & 7;
    const int n     = half * 8 + n_loc;       // fixed per thread
    const int g     = tid >> 3;               // 0..127

    // Per-level frequencies/phases in registers (reused 16 iters).
    float G0[3], G1[3], G2[3], Hr[3];
#pragma unroll
    for (int m = 0; m < 3; ++m) {
        G0[m] = G[0 * 48 + m * 16 + n];
        G1[m] = G[1 * 48 + m * 16 + n];
        G2[m] = G[2 * 48 + m * 16 + n];
        Hr[m] = H[m * 16 + n];
    }
    __syncthreads();

    float2* __restrict__ out2 = (float2*)out;
    const __half2* lrow = &lds[n_loc * WPAD];

    // 16 iterations, b stride 512*128 = 65536; 1-ahead x prefetch.
    int b = blk * 128 + g;
    float x0 = x[b * 3 + 0];
    float x1 = x[b * 3 + 1];
    float x2 = x[b * 3 + 2];

#pragma unroll 2
    for (int i = 0; i < 16; ++i) {
        const int bn = b + 512 * 128;
        const int bs = (i < 15) ? bn : b;     // clamp: no OOB on last iter
        float y0 = x[bs * 3 + 0];             // next iter's x, issued early
        float y1 = x[bs * 3 + 1];
        float y2 = x[bs * 3 + 2];

        float p = 1.0f;
#pragma unroll
        for (int m = 0; m < 3; ++m) {
            float a = fmaf(x0, G0[m], fmaf(x1, G1[m], fmaf(x2, G2[m], Hr[m])));
            p *= hw_sin(a);
        }

        float ix = fmaf(p, 500.0f, 499.5f);                // [-0.5, 999.5]
        float xf = floorf(ix);
        float t  = ix - xf;
        int base = (int)xf;                                // [-1, 999]
        base = min(max(base, -1), 999);                    // cheap insurance

        // Factored Keys weights:
        // w0 = A t u^2, w3 = A t^2 u, w1 = ((A+2)t-(A+3))t^2+1, w2 = 1-rest
        float u   = 1.0f - t;
        float tu  = t * u;
        float atu = A_C * tu;
        float w0  = atu * u;
        float w3  = atu * t;
        float w1  = fmaf(fmaf(A_C + 2.0f, t, -(A_C + 3.0f)), t * t, 1.0f);
        float w2  = 1.0f - w0 - w1 - w3;

        // 4 consecutive padded taps starting at padded index base+1 >= 0.
        const __half2* tap = lrow + (base + 1);
        float2 v0 = __half22float2(tap[0]);
        float2 v1 = __half22float2(tap[1]);
        float2 v2 = __half22float2(tap[2]);
        float2 v3 = __half22float2(tap[3]);

        float o0 = v0.x * w0, o1 = v0.y * w0;
        o0 = fmaf(v1.x, w1, o0); o1 = fmaf(v1.y, w1, o1);
        o0 = fmaf(v2.x, w2, o0); o1 = fmaf(v2.y, w2, o1);
        o0 = fmaf(v3.x, w3, o0); o1 = fmaf(v3.y, w3, o1);

        // out[b, n, c] flat = b*32 + n*2 + c -> float2 at b*16 + n
        // wave = 8 b x 8 n -> 1KB contiguous store per wave.
        out2[b * 16 + n] = make_float2(o0, o1);

        b = bn; x0 = y0; x1 = y1; x2 = y2;
    }
}

extern "C" void kernel_launch(void* const* d_in, const int* in_sizes, int n_in,
                              void* d_out, int out_size, void* d_ws, size_t ws_size,
                              hipStream_t stream) {
    const float* x     = (const float*)d_in[0];
    const float* grids = (const float*)d_in[1];
    const float* G     = (const float*)d_in[2];
    const float* H     = (const float*)d_in[3];
    float* out = (float*)d_out;
    trig_hashgrid<<<1024, BLK, 0, stream>>>(x, grids, G, H, out);
}